// Round 4
// baseline (689.377 us; speedup 1.0000x reference)
//
#include <hip/hip_runtime.h>

typedef short short8 __attribute__((ext_vector_type(8)));
typedef float float4v __attribute__((ext_vector_type(4)));

__device__ __forceinline__ unsigned short f2bf(float f) {
    unsigned int u = __float_as_uint(f);
    u += 0x7fffu + ((u >> 16) & 1u);   // RNE
    return (unsigned short)(u >> 16);
}
__device__ __forceinline__ float bfs(const unsigned short* p) {
    return __uint_as_float(((unsigned int)*p) << 16);
}
__device__ __forceinline__ float4v mfma16(short8 a, short8 b, float4v c) {
    return __builtin_amdgcn_mfma_f32_16x16x32_bf16(a, b, c, 0, 0, 0);
}

// pack qkv_w (288x96) / proj_w (96x96) fp32 -> bf16 MFMA A-fragment order
__global__ void prep_pack(const float* __restrict__ qkv_w,
                          const float* __restrict__ proj_w,
                          short* __restrict__ apq, short* __restrict__ app) {
    const int i = blockIdx.x * 256 + threadIdx.x;
    if (i < 3456) {
        const int rem = i % 192, f = rem / 64, lane = rem % 64;
        const int m = (i / 192) * 16 + (lane & 15);
        const int kb = f * 32 + ((lane >> 4) & 3) * 8;
        const float* s = qkv_w + m * 96 + kb;
        short8 o;
        #pragma unroll
        for (int j = 0; j < 8; ++j) o[j] = (short)f2bf(s[j]);
        *(short8*)(apq + i * 8) = o;
    } else if (i < 4608) {
        const int i2 = i - 3456;
        const int rem = i2 % 192, f = rem / 64, lane = rem % 64;
        const int m = (i2 / 192) * 16 + (lane & 15);
        const int kb = f * 32 + ((lane >> 4) & 3) * 8;
        const float* s = proj_w + m * 96 + kb;
        short8 o;
        #pragma unroll
        for (int j = 0; j < 8; ++j) o[j] = (short)f2bf(s[j]);
        *(short8*)(app + i2 * 8) = o;
    }
}

// One block per 8x8 window, 256 threads = 4 waves. LDS 40,080 B -> 4 blocks/CU.
__global__ __launch_bounds__(256, 4)
void fused_win_attn(const float* __restrict__ x,
                    const short* __restrict__ apq,
                    const float* __restrict__ qkv_b,
                    const float* __restrict__ dw_w,
                    const float* __restrict__ dw_b,
                    const short* __restrict__ app,
                    const float* __restrict__ proj_b,
                    const float* __restrict__ temperature,
                    const float* __restrict__ rel_bias,
                    float* __restrict__ yout)
{
    __shared__ __align__(16) unsigned char smem[40080];
    // Region X [0,13312): sxT (staging) then per-head union:
    //   raw  [48][100] halo layout (P1W-P2R)      bytes [0,9600)
    //   sST  [64][72]  (P4W-P5R)                  bytes [0,9216)
    //   stmp [16][72]  (P4W-P5R)                  bytes [9216,11520)
    //   ach  [16][24]  (P3W-P4R)                  bytes [11520,12288)
    //   sred [4][64] f32 (P3W-P4R)                bytes [12288,13312)
    unsigned short* sxT   = (unsigned short*)smem;
    unsigned short* raw   = (unsigned short*)smem;
    unsigned short* sST   = (unsigned short*)smem;
    unsigned short* stmp  = (unsigned short*)(smem + 9216);
    unsigned short* ach   = (unsigned short*)(smem + 11520);
    float*          sred  = (float*)(smem + 12288);
    unsigned short* soutT = (unsigned short*)(smem + 13312);  // [64][104] persistent
    unsigned short* sqkv  = (unsigned short*)(smem + 26624);  // [32][72]
    unsigned short* qnT   = (unsigned short*)(smem + 31232);  // [64][16]
    unsigned short* knT   = (unsigned short*)(smem + 33280);  // [64][16]
    unsigned short* vT    = (unsigned short*)(smem + 35328);  // [64][16]
    unsigned short* sbias = (unsigned short*)(smem + 37376);  // [1352]

    const int tid  = threadIdx.x;
    const int lane = tid & 63;
    const int g    = tid >> 6;
    const int quad = lane >> 4;
    const int l15  = lane & 15;
    // XCD-pair swizzle: adjacent windows (sharing 64B x-lines) on same XCD
    const int bx = blockIdx.x;
    const int wi = (bx & ~15) | ((bx & 7) << 1) | ((bx >> 3) & 1);
    const int y0 = (wi >> 6) << 3;
    const int x0 = (wi & 63) << 3;
    const int py = lane >> 3, px = lane & 7;

    // ---- stage x^T (bf16) into region X; rel_bias bf16 ----
    for (int r = tid; r < 1536; r += 256) {
        const int c = r >> 4, p0 = (r & 15) * 4;
        float4 v = *(const float4*)(x + c * 262144 + (y0 + (p0 >> 3)) * 512 + x0 + (p0 & 7));
        sxT[(p0 + 0) * 104 + c] = f2bf(v.x);
        sxT[(p0 + 1) * 104 + c] = f2bf(v.y);
        sxT[(p0 + 2) * 104 + c] = f2bf(v.z);
        sxT[(p0 + 3) * 104 + c] = f2bf(v.w);
    }
    for (int r = tid; r < 1350; r += 256) sbias[r] = f2bf(rel_bias[r]);
    __syncthreads();

    // hoist qkv/proj B-fragments (same for all heads) and dwconv offsets
    short8 bfx[3];
    #pragma unroll
    for (int f = 0; f < 3; ++f)
        bfx[f] = *(const short8*)(sxT + (g * 16 + l15) * 104 + f * 32 + quad * 8);
    int doff[9];
    #pragma unroll
    for (int di = 0; di < 3; ++di)
        #pragma unroll
        for (int dj = 0; dj < 3; ++dj)
            doff[di * 3 + dj] = (py + di) * 10 + (px + dj);
    __syncthreads();   // region X now reusable

    for (int h = 0; h < 6; ++h) {
        // ---- P1: zero halo ring; qkv GEMM -> raw (halo interior) ----
        for (int r = tid; r < 1728; r += 256) {
            const int ch = r / 36, k = r % 36;
            int cell;
            if (k < 10)      cell = k;                 // row 0
            else if (k < 20) cell = 90 + (k - 10);     // row 9
            else if (k < 28) cell = (k - 19) * 10;     // col 0, rows 1..8
            else             cell = (k - 27) * 10 + 9; // col 9, rows 1..8
            raw[ch * 100 + cell] = 0;
        }
        {
            const int p = g * 16 + l15;                // this wave's pixel
            const int wcell = (p >> 3) * 10 + (p & 7) + 11;
            #pragma unroll
            for (int t = 0; t < 3; ++t) {
                float4v acc = {0.f, 0.f, 0.f, 0.f};
                #pragma unroll
                for (int f = 0; f < 3; ++f) {
                    short8 af = *(const short8*)(apq + (((t * 6 + h) * 3 + f) * 64 + lane) * 8);
                    acc = mfma16(af, bfx[f], acc);
                }
                #pragma unroll
                for (int reg = 0; reg < 4; ++reg) {
                    const int rr = quad * 4 + reg;
                    raw[(t * 16 + rr) * 100 + wcell] =
                        f2bf(acc[reg] + qkv_b[t * 96 + h * 16 + rr]);
                }
            }
        }
        __syncthreads();   // B1

        // ---- P2: dwconv (halo ds_reads, SGPR taps) + L2 norm + transposes ----
        {
            unsigned int qw0 = 0, qw1 = 0, kw0 = 0, kw1 = 0, vw0 = 0, vw1 = 0;
            #pragma unroll
            for (int r = 0; r < 12; ++r) {
                const int j = (r >> 2) * 16 + 4 * g + (r & 3);   // wave-contig rows
                const int O = __builtin_amdgcn_readfirstlane((j >> 4) * 96 + h * 16 + (j & 15));
                const float* wq = dw_w + O * 9;
                float a = dw_b[O];
                const unsigned short* rbase = raw + j * 100;
                #pragma unroll
                for (int t = 0; t < 9; ++t)
                    a = fmaf(wq[t], bfs(rbase + doff[t]), a);
                if (r < 8) {   // q,k rows: L2-normalize over N=64
                    float ss = a * a;
                    #pragma unroll
                    for (int m = 1; m < 64; m <<= 1) ss += __shfl_xor(ss, m, 64);
                    a = a * (1.f / fmaxf(sqrtf(ss), 1e-12f));
                    sqkv[j * 72 + lane] = f2bf(a);
                }
                const unsigned int bv = f2bf(a);
                if      (r == 0)  qw0 |= bv;          else if (r == 1)  qw0 |= bv << 16;
                else if (r == 2)  qw1 |= bv;          else if (r == 3)  qw1 |= bv << 16;
                else if (r == 4)  kw0 |= bv;          else if (r == 5)  kw0 |= bv << 16;
                else if (r == 6)  kw1 |= bv;          else if (r == 7)  kw1 |= bv << 16;
                else if (r == 8)  vw0 |= bv;          else if (r == 9)  vw0 |= bv << 16;
                else if (r == 10) vw1 |= bv;          else              vw1 |= bv << 16;
            }
            uint2 uq; uq.x = qw0; uq.y = qw1;
            uint2 uk; uk.x = kw0; uk.y = kw1;
            uint2 uv; uv.x = vw0; uv.y = vw1;
            *(uint2*)(qnT + lane * 16 + 4 * g) = uq;
            *(uint2*)(knT + lane * 16 + 4 * g) = uk;
            *(uint2*)(vT  + lane * 16 + 4 * g) = uv;
        }
        __syncthreads();   // B2

        // ---- P3: S^T logits + exp + partial sums; wave0: channel attn ----
        float ex[16];
        {
            short8 ak = {0, 0, 0, 0, 0, 0, 0, 0};
            if (lane < 32) ak = *(const short8*)(knT + (g * 16 + l15) * 16 + quad * 8);
            #pragma unroll
            for (int nt = 0; nt < 4; ++nt) {
                short8 bq = {0, 0, 0, 0, 0, 0, 0, 0};
                if (lane < 32) bq = *(const short8*)(qnT + (nt * 16 + l15) * 16 + quad * 8);
                float4v cs = {0.f, 0.f, 0.f, 0.f};
                cs = mfma16(ak, bq, cs);
                float ps = 0.f;
                #pragma unroll
                for (int reg = 0; reg < 4; ++reg) {
                    const int m = g * 16 + quad * 4 + reg;
                    const int n = nt * 16 + l15;
                    const int idx = ((n >> 3) - (m >> 3) + 7) * 15 + ((n & 7) - (m & 7) + 7);
                    const float e = __expf(cs[reg] + bfs(sbias + idx * 6 + h));
                    ex[nt * 4 + reg] = e;
                    ps += e;
                }
                ps += __shfl_xor(ps, 16, 64);
                ps += __shfl_xor(ps, 32, 64);
                if (lane < 16) sred[g * 64 + nt * 16 + lane] = ps;
            }
        }
        if (g == 0) {
            short8 a0 = *(const short8*)(sqkv + l15 * 72 + quad * 8);
            short8 a1 = *(const short8*)(sqkv + l15 * 72 + 32 + quad * 8);
            short8 b0 = *(const short8*)(sqkv + (16 + l15) * 72 + quad * 8);
            short8 b1 = *(const short8*)(sqkv + (16 + l15) * 72 + 32 + quad * 8);
            float4v cc = {0.f, 0.f, 0.f, 0.f};
            cc = mfma16(a0, b0, cc);
            cc = mfma16(a1, b1, cc);
            const float tp = temperature[h];
            #pragma unroll
            for (int reg = 0; reg < 4; ++reg) {
                const float e = __expf(cc[reg] * tp);
                float se = e;
                #pragma unroll
                for (int m = 1; m < 16; m <<= 1) se += __shfl_xor(se, m, 64);
                ach[(quad * 4 + reg) * 24 + l15] = f2bf(e / se);
            }
        }
        __syncthreads();   // B3

        // ---- P4: normalize S^T -> sST; tmp = attn_ch @ v -> stmp ----
        #pragma unroll
        for (int nt = 0; nt < 4; ++nt) {
            const int n = nt * 16 + l15;
            const float inv = 1.f / (sred[n] + sred[64 + n] + sred[128 + n] + sred[192 + n]);
            #pragma unroll
            for (int reg = 0; reg < 4; ++reg)
                sST[(g * 16 + quad * 4 + reg) * 72 + n] = f2bf(ex[nt * 4 + reg] * inv);
        }
        {
            short8 af = {0, 0, 0, 0, 0, 0, 0, 0}, bv = {0, 0, 0, 0, 0, 0, 0, 0};
            if (lane < 32) {
                af = *(const short8*)(ach + l15 * 24 + quad * 8);
                bv = *(const short8*)(vT + (g * 16 + l15) * 16 + quad * 8);
            }
            float4v ct = {0.f, 0.f, 0.f, 0.f};
            ct = mfma16(af, bv, ct);
            #pragma unroll
            for (int reg = 0; reg < 4; ++reg)
                stmp[(quad * 4 + reg) * 72 + g * 16 + l15] = f2bf(ct[reg]);
        }
        __syncthreads();   // B4

        // ---- P5: out_h^T = (tmp @ S)^T -> soutT ----
        {
            short8 a0 = *(const short8*)(stmp + l15 * 72 + quad * 8);
            short8 a1 = *(const short8*)(stmp + l15 * 72 + 32 + quad * 8);
            short8 b0 = *(const short8*)(sST + (g * 16 + l15) * 72 + quad * 8);
            short8 b1 = *(const short8*)(sST + (g * 16 + l15) * 72 + 32 + quad * 8);
            float4v co = {0.f, 0.f, 0.f, 0.f};
            co = mfma16(a0, b0, co);
            co = mfma16(a1, b1, co);
            #pragma unroll
            for (int reg = 0; reg < 4; ++reg)
                soutT[(g * 16 + l15) * 104 + h * 16 + quad * 4 + reg] = f2bf(co[reg]);
        }
        __syncthreads();   // B5 (protects region X for next head)
    }

    // ---- proj GEMM (96x64, K=96) + bias + window-reverse store ----
    {
        short8 pb[3];
        #pragma unroll
        for (int f = 0; f < 3; ++f)
            pb[f] = *(const short8*)(soutT + (g * 16 + l15) * 104 + f * 32 + quad * 8);
        const int p = g * 16 + l15;
        float* outbase = yout + (y0 + (p >> 3)) * 512 + x0 + (p & 7);
        #pragma unroll
        for (int mt = 0; mt < 6; ++mt) {
            float4v acc = {0.f, 0.f, 0.f, 0.f};
            #pragma unroll
            for (int f = 0; f < 3; ++f) {
                short8 af = *(const short8*)(app + ((mt * 3 + f) * 64 + lane) * 8);
                acc = mfma16(af, pb[f], acc);
            }
            #pragma unroll
            for (int reg = 0; reg < 4; ++reg) {
                const int o = mt * 16 + quad * 4 + reg;
                outbase[o * 262144] = acc[reg] + proj_b[o];
            }
        }
    }
}

extern "C" void kernel_launch(void* const* d_in, const int* in_sizes, int n_in,
                              void* d_out, int out_size, void* d_ws, size_t ws_size,
                              hipStream_t stream) {
    const float* x      = (const float*)d_in[0];
    const float* qkv_w  = (const float*)d_in[1];
    const float* qkv_b  = (const float*)d_in[2];
    const float* dw_w   = (const float*)d_in[3];
    const float* dw_b   = (const float*)d_in[4];
    const float* proj_w = (const float*)d_in[5];
    const float* proj_b = (const float*)d_in[6];
    const float* temp   = (const float*)d_in[7];
    const float* relb   = (const float*)d_in[8];
    float* o = (float*)d_out;

    short* apq = (short*)d_ws;              // 27648 bf16
    short* app = apq + 27648;               // 9216 bf16

    hipLaunchKernelGGL(prep_pack, dim3(18), dim3(256), 0, stream, qkv_w, proj_w, apq, app);
    hipLaunchKernelGGL(fused_win_attn, dim3(4096), dim3(256), 0, stream,
                       x, apq, qkv_b, dw_w, dw_b, app, proj_b, temp, relb, o);
}

// Round 5
// 641.374 us; speedup vs baseline: 1.0748x; 1.0748x over previous
//
#include <hip/hip_runtime.h>

typedef short short8 __attribute__((ext_vector_type(8)));
typedef float float4v __attribute__((ext_vector_type(4)));

__device__ __forceinline__ unsigned short f2bf(float f) {
    unsigned int u = __float_as_uint(f);
    u += 0x7fffu + ((u >> 16) & 1u);   // RNE
    return (unsigned short)(u >> 16);
}
__device__ __forceinline__ float bfs(const unsigned short* p) {
    return __uint_as_float(((unsigned int)*p) << 16);
}
__device__ __forceinline__ float4v mfma16(short8 a, short8 b, float4v c) {
    return __builtin_amdgcn_mfma_f32_16x16x32_bf16(a, b, c, 0, 0, 0);
}

// pack qkv_w (288x96) / proj_w (96x96) fp32 -> bf16 MFMA A-fragment order
__global__ void prep_pack(const float* __restrict__ qkv_w,
                          const float* __restrict__ proj_w,
                          short* __restrict__ apq, short* __restrict__ app) {
    const int i = blockIdx.x * 256 + threadIdx.x;
    if (i < 3456) {
        const int rem = i % 192, f = rem / 64, lane = rem % 64;
        const int m = (i / 192) * 16 + (lane & 15);
        const int kb = f * 32 + ((lane >> 4) & 3) * 8;
        const float* s = qkv_w + m * 96 + kb;
        short8 o;
        #pragma unroll
        for (int j = 0; j < 8; ++j) o[j] = (short)f2bf(s[j]);
        *(short8*)(apq + i * 8) = o;
    } else if (i < 4608) {
        const int i2 = i - 3456;
        const int rem = i2 % 192, f = rem / 64, lane = rem % 64;
        const int m = (i2 / 192) * 16 + (lane & 15);
        const int kb = f * 32 + ((lane >> 4) & 3) * 8;
        const float* s = proj_w + m * 96 + kb;
        short8 o;
        #pragma unroll
        for (int j = 0; j < 8; ++j) o[j] = (short)f2bf(s[j]);
        *(short8*)(app + i2 * 8) = o;
    }
}

// One block per 8x8 window, 256 threads = 4 waves. LDS 40,080 B -> 4 blocks/CU.
__global__ __launch_bounds__(256, 4)
void fused_win_attn(const float* __restrict__ x,
                    const short* __restrict__ apq,
                    const float* __restrict__ qkv_b,
                    const float* __restrict__ dw_w,
                    const float* __restrict__ dw_b,
                    const short* __restrict__ app,
                    const float* __restrict__ proj_b,
                    const float* __restrict__ temperature,
                    const float* __restrict__ rel_bias,
                    float* __restrict__ yout)
{
    __shared__ __align__(16) unsigned char smem[40080];
    // Region X [0,13312): sxT (staging) then per-head union:
    //   raw  [48][100] halo layout (P1W-P2R)   bytes [0,9600)
    //   sST  [64][72]  raw exp     (P3W-P5R)   bytes [0,9216)
    //   stmp [16][72]  tmp/l[n]    (P4W-P5R)   bytes [9216,11520)
    //   ach  [16][24]  attn_ch     (P3W-P4R)   bytes [11520,12288)
    //   sred [4][64] f32 partials  (P3W-P4R)   bytes [12288,13312)
    unsigned short* sxT   = (unsigned short*)smem;
    unsigned short* raw   = (unsigned short*)smem;
    unsigned short* sST   = (unsigned short*)smem;
    unsigned short* stmp  = (unsigned short*)(smem + 9216);
    unsigned short* ach   = (unsigned short*)(smem + 11520);
    float*          sred  = (float*)(smem + 12288);
    unsigned short* soutT = (unsigned short*)(smem + 13312);  // [64][104] persistent
    unsigned short* sqkv  = (unsigned short*)(smem + 26624);  // [32][72]
    unsigned short* qnT   = (unsigned short*)(smem + 31232);  // [64][16]
    unsigned short* knT   = (unsigned short*)(smem + 33280);  // [64][16]
    unsigned short* vT    = (unsigned short*)(smem + 35328);  // [64][16]
    unsigned short* sbias = (unsigned short*)(smem + 37376);  // [1352]

    const int tid  = threadIdx.x;
    const int lane = tid & 63;
    const int g    = tid >> 6;
    const int quad = lane >> 4;
    const int l15  = lane & 15;
    const int wi = blockIdx.x;
    const int y0 = (wi >> 6) << 3;
    const int x0 = (wi & 63) << 3;
    const int py = lane >> 3, px = lane & 7;

    // ---- stage x^T (bf16) into region X; rel_bias bf16 ----
    for (int r = tid; r < 1536; r += 256) {
        const int c = r >> 4, p0 = (r & 15) * 4;
        float4 v = *(const float4*)(x + c * 262144 + (y0 + (p0 >> 3)) * 512 + x0 + (p0 & 7));
        sxT[(p0 + 0) * 104 + c] = f2bf(v.x);
        sxT[(p0 + 1) * 104 + c] = f2bf(v.y);
        sxT[(p0 + 2) * 104 + c] = f2bf(v.z);
        sxT[(p0 + 3) * 104 + c] = f2bf(v.w);
    }
    for (int r = tid; r < 1350; r += 256) sbias[r] = f2bf(rel_bias[r]);
    __syncthreads();

    // hoist qkv/proj B-fragments (same for all heads)
    short8 bfx[3];
    #pragma unroll
    for (int f = 0; f < 3; ++f)
        bfx[f] = *(const short8*)(sxT + (g * 16 + l15) * 104 + f * 32 + quad * 8);
    __syncthreads();   // region X now reusable

    for (int h = 0; h < 6; ++h) {
        // ---- P1: zero halo ring; qkv GEMM -> raw interior ----
        for (int r = tid; r < 1728; r += 256) {
            const int ch = r / 36, k = r % 36;
            int cell;
            if (k < 10)      cell = k;
            else if (k < 20) cell = 90 + (k - 10);
            else if (k < 28) cell = (k - 19) * 10;
            else             cell = (k - 27) * 10 + 9;
            raw[ch * 100 + cell] = 0;
        }
        {
            const int p = g * 16 + l15;
            const int wcell = (p >> 3) * 10 + (p & 7) + 11;
            #pragma unroll
            for (int t = 0; t < 3; ++t) {
                float4v acc = {0.f, 0.f, 0.f, 0.f};
                #pragma unroll
                for (int f = 0; f < 3; ++f) {
                    short8 af = *(const short8*)(apq + (((t * 6 + h) * 3 + f) * 64 + lane) * 8);
                    acc = mfma16(af, bfx[f], acc);
                }
                #pragma unroll
                for (int reg = 0; reg < 4; ++reg) {
                    const int rr = quad * 4 + reg;
                    raw[(t * 16 + rr) * 100 + wcell] =
                        f2bf(acc[reg] + qkv_b[t * 96 + h * 16 + rr]);
                }
            }
        }
        __syncthreads();   // B1

        // ---- P2: dwconv (immediate-offset halo reads) + L2 norm + transposes ----
        {
            unsigned int qw0 = 0, qw1 = 0, kw0 = 0, kw1 = 0, vw0 = 0, vw1 = 0;
            #pragma unroll
            for (int r = 0; r < 12; ++r) {
                const int j = (r >> 2) * 16 + 4 * g + (r & 3);   // wave-contig rows
                const int O = __builtin_amdgcn_readfirstlane((j >> 4) * 96 + h * 16 + (j & 15));
                const float* wq = dw_w + O * 9;
                float a = dw_b[O];
                const unsigned short* rbase = raw + j * 100 + py * 10 + px;
                a = fmaf(wq[0], bfs(rbase +  0), a);
                a = fmaf(wq[1], bfs(rbase +  1), a);
                a = fmaf(wq[2], bfs(rbase +  2), a);
                a = fmaf(wq[3], bfs(rbase + 10), a);
                a = fmaf(wq[4], bfs(rbase + 11), a);
                a = fmaf(wq[5], bfs(rbase + 12), a);
                a = fmaf(wq[6], bfs(rbase + 20), a);
                a = fmaf(wq[7], bfs(rbase + 21), a);
                a = fmaf(wq[8], bfs(rbase + 22), a);
                if (r < 8) {   // q,k rows: L2-normalize over N=64
                    float ss = a * a;
                    #pragma unroll
                    for (int m = 1; m < 64; m <<= 1) ss += __shfl_xor(ss, m, 64);
                    a = a * (1.f / fmaxf(sqrtf(ss), 1e-12f));
                    sqkv[j * 72 + lane] = f2bf(a);
                }
                const unsigned int bv = f2bf(a);
                if      (r == 0)  qw0 |= bv;          else if (r == 1)  qw0 |= bv << 16;
                else if (r == 2)  qw1 |= bv;          else if (r == 3)  qw1 |= bv << 16;
                else if (r == 4)  kw0 |= bv;          else if (r == 5)  kw0 |= bv << 16;
                else if (r == 6)  kw1 |= bv;          else if (r == 7)  kw1 |= bv << 16;
                else if (r == 8)  vw0 |= bv;          else if (r == 9)  vw0 |= bv << 16;
                else if (r == 10) vw1 |= bv;          else              vw1 |= bv << 16;
            }
            uint2 uq; uq.x = qw0; uq.y = qw1;
            uint2 uk; uk.x = kw0; uk.y = kw1;
            uint2 uv; uv.x = vw0; uv.y = vw1;
            *(uint2*)(qnT + lane * 16 + 4 * g) = uq;
            *(uint2*)(knT + lane * 16 + 4 * g) = uk;
            *(uint2*)(vT  + lane * 16 + 4 * g) = uv;
        }
        __syncthreads();   // B2

        // ---- P3: S^T logits -> exp straight to LDS + partial sums; wave0: ch-attn ----
        {
            short8 ak = {0, 0, 0, 0, 0, 0, 0, 0};
            if (lane < 32) ak = *(const short8*)(knT + (g * 16 + l15) * 16 + quad * 8);
            #pragma unroll
            for (int nt = 0; nt < 4; ++nt) {
                short8 bq = {0, 0, 0, 0, 0, 0, 0, 0};
                if (lane < 32) bq = *(const short8*)(qnT + (nt * 16 + l15) * 16 + quad * 8);
                float4v cs = {0.f, 0.f, 0.f, 0.f};
                cs = mfma16(ak, bq, cs);
                float ps = 0.f;
                #pragma unroll
                for (int reg = 0; reg < 4; ++reg) {
                    const int m = g * 16 + quad * 4 + reg;
                    const int n = nt * 16 + l15;
                    const int idx = ((n >> 3) - (m >> 3) + 7) * 15 + ((n & 7) - (m & 7) + 7);
                    const float e = __expf(cs[reg] + bfs(sbias + idx * 6 + h));
                    sST[m * 72 + n] = f2bf(e);     // unnormalized
                    ps += e;
                }
                ps += __shfl_xor(ps, 16, 64);
                ps += __shfl_xor(ps, 32, 64);
                if (lane < 16) sred[g * 64 + nt * 16 + lane] = ps;
            }
        }
        if (g == 0) {
            short8 a0 = *(const short8*)(sqkv + l15 * 72 + quad * 8);
            short8 a1 = *(const short8*)(sqkv + l15 * 72 + 32 + quad * 8);
            short8 b0 = *(const short8*)(sqkv + (16 + l15) * 72 + quad * 8);
            short8 b1 = *(const short8*)(sqkv + (16 + l15) * 72 + 32 + quad * 8);
            float4v cc = {0.f, 0.f, 0.f, 0.f};
            cc = mfma16(a0, b0, cc);
            cc = mfma16(a1, b1, cc);
            const float tp = temperature[h];
            #pragma unroll
            for (int reg = 0; reg < 4; ++reg) {
                const float e = __expf(cc[reg] * tp);
                float se = e;
                #pragma unroll
                for (int m = 1; m < 16; m <<= 1) se += __shfl_xor(se, m, 64);
                ach[(quad * 4 + reg) * 24 + l15] = f2bf(e / se);
            }
        }
        __syncthreads();   // B3

        // ---- P4: tmp = (attn_ch @ v) / l[n]  -> stmp  (denominator folded here) ----
        {
            const int n = g * 16 + l15;
            const float inv = 1.f / (sred[n] + sred[64 + n] + sred[128 + n] + sred[192 + n]);
            short8 af = {0, 0, 0, 0, 0, 0, 0, 0}, bv = {0, 0, 0, 0, 0, 0, 0, 0};
            if (lane < 32) {
                af = *(const short8*)(ach + l15 * 24 + quad * 8);
                bv = *(const short8*)(vT + (g * 16 + l15) * 16 + quad * 8);
            }
            float4v ct = {0.f, 0.f, 0.f, 0.f};
            ct = mfma16(af, bv, ct);
            #pragma unroll
            for (int reg = 0; reg < 4; ++reg)
                stmp[(quad * 4 + reg) * 72 + g * 16 + l15] = f2bf(ct[reg] * inv);
        }
        __syncthreads();   // B4

        // ---- P5: out_h^T = (tmp @ S)^T -> soutT ----
        {
            short8 a0 = *(const short8*)(stmp + l15 * 72 + quad * 8);
            short8 a1 = *(const short8*)(stmp + l15 * 72 + 32 + quad * 8);
            short8 b0 = *(const short8*)(sST + (g * 16 + l15) * 72 + quad * 8);
            short8 b1 = *(const short8*)(sST + (g * 16 + l15) * 72 + 32 + quad * 8);
            float4v co = {0.f, 0.f, 0.f, 0.f};
            co = mfma16(a0, b0, co);
            co = mfma16(a1, b1, co);
            #pragma unroll
            for (int reg = 0; reg < 4; ++reg)
                soutT[(g * 16 + l15) * 104 + h * 16 + quad * 4 + reg] = f2bf(co[reg]);
        }
        __syncthreads();   // B5 (protects region X for next head)
    }

    // ---- proj GEMM (96x64, K=96) + bias + window-reverse store ----
    {
        short8 pb[3];
        #pragma unroll
        for (int f = 0; f < 3; ++f)
            pb[f] = *(const short8*)(soutT + (g * 16 + l15) * 104 + f * 32 + quad * 8);
        const int p = g * 16 + l15;
        float* outbase = yout + (y0 + (p >> 3)) * 512 + x0 + (p & 7);
        #pragma unroll
        for (int mt = 0; mt < 6; ++mt) {
            float4v acc = {0.f, 0.f, 0.f, 0.f};
            #pragma unroll
            for (int f = 0; f < 3; ++f) {
                short8 af = *(const short8*)(app + ((mt * 3 + f) * 64 + lane) * 8);
                acc = mfma16(af, pb[f], acc);
            }
            #pragma unroll
            for (int reg = 0; reg < 4; ++reg) {
                const int o = mt * 16 + quad * 4 + reg;
                outbase[o * 262144] = acc[reg] + proj_b[o];
            }
        }
    }
}

extern "C" void kernel_launch(void* const* d_in, const int* in_sizes, int n_in,
                              void* d_out, int out_size, void* d_ws, size_t ws_size,
                              hipStream_t stream) {
    const float* x      = (const float*)d_in[0];
    const float* qkv_w  = (const float*)d_in[1];
    const float* qkv_b  = (const float*)d_in[2];
    const float* dw_w   = (const float*)d_in[3];
    const float* dw_b   = (const float*)d_in[4];
    const float* proj_w = (const float*)d_in[5];
    const float* proj_b = (const float*)d_in[6];
    const float* temp   = (const float*)d_in[7];
    const float* relb   = (const float*)d_in[8];
    float* o = (float*)d_out;

    short* apq = (short*)d_ws;              // 27648 bf16
    short* app = apq + 27648;               // 9216 bf16

    hipLaunchKernelGGL(prep_pack, dim3(18), dim3(256), 0, stream, qkv_w, proj_w, apq, app);
    hipLaunchKernelGGL(fused_win_attn, dim3(4096), dim3(256), 0, stream,
                       x, apq, qkv_b, dw_w, dw_b, app, proj_b, temp, relb, o);
}